// Round 3
// baseline (291.247 us; speedup 1.0000x reference)
//
#include <hip/hip_runtime.h>
#include <math.h>

#define DIMK 2048
#define NSEQ 4096

typedef short bf16x8 __attribute__((ext_vector_type(8)));
typedef float f32x16 __attribute__((ext_vector_type(16)));
typedef unsigned short u16;

__device__ __forceinline__ u16 f32_to_bf16(float f) {
  unsigned u = __float_as_uint(f);
  u += 0x7fffu + ((u >> 16) & 1u);   // round-to-nearest-even
  return (u16)(u >> 16);
}

__device__ __forceinline__ void async16(const u16* g, u16* l) {
  __builtin_amdgcn_global_load_lds(
      (const __attribute__((address_space(1))) unsigned int*)g,
      (__attribute__((address_space(3))) unsigned int*)l,
      16, 0, 0);
}

// -------- fused fp32 -> bf16 cast for x, Wq, Wk (one launch) --------
__global__ __launch_bounds__(256) void cast3_f32_bf16(
    const float* __restrict__ x, const float* __restrict__ wq,
    const float* __restrict__ wk, u16* __restrict__ xb,
    u16* __restrict__ wqb, u16* __restrict__ wkb) {
  const int xN4 = NSEQ * DIMK / 4;
  const int wN4 = DIMK * DIMK / 4;
  int i = blockIdx.x * 256 + threadIdx.x;
  const float* src;
  u16* dst;
  int j;
  if (i < xN4) { src = x; dst = xb; j = i; }
  else if (i < xN4 + wN4) { src = wq; dst = wqb; j = i - xN4; }
  else { src = wk; dst = wkb; j = i - xN4 - wN4; }
  float4 v = ((const float4*)src)[j];
  ushort4 o;
  o.x = f32_to_bf16(v.x);
  o.y = f32_to_bf16(v.y);
  o.z = f32_to_bf16(v.z);
  o.w = f32_to_bf16(v.w);
  ((ushort4*)dst)[j] = o;
}

// ---- shared NT bf16 GEMM mainloop: 128x128 tile, BK=64, swizzled LDS,
// 32x32x16 MFMA (2x2 accums of 32x32 per wave = 64x64 wave tile).
// LDS layout: slot s holds (row = s>>3, logical kchunk = (s&7)^(row&7)),
// 8 bf16 per slot — frag reads are <=2-way per 16-lane phase (free).
__device__ __forceinline__ void gemm_mainloop_128(
    const u16* __restrict__ Abase, const u16* __restrict__ Bbase,
    u16* sA, u16* sB, f32x16 acc[2][2], int tid, int wm, int wn, int lane) {
  const int K = DIMK;
  int rowS[4], glOff[4];
#pragma unroll
  for (int c = 0; c < 4; ++c) {
    int s = c * 256 + tid;
    int row = s >> 3;
    int l = (s & 7) ^ (row & 7);     // logical kchunk fetched into this slot
    rowS[c] = s;
    glOff[c] = row * K + l * 8;
  }
  const int r31 = lane & 31;
  const int q = lane >> 5;          // k-half within frag
  const int f7 = lane & 7;
  int rowA[2], rowB[2], colOff[4];
#pragma unroll
  for (int i = 0; i < 2; ++i) {
    rowA[i] = (wm + i * 32 + r31) * 64;
    rowB[i] = (wn + i * 32 + r31) * 64;
  }
#pragma unroll
  for (int ks = 0; ks < 4; ++ks)
    colOff[ks] = (((ks << 1) | q) ^ f7) * 8;   // physical kchunk * 8

  for (int k0 = 0; k0 < K; k0 += 64) {
#pragma unroll
    for (int c = 0; c < 4; ++c) {
      async16(Abase + glOff[c] + k0, sA + rowS[c] * 8);
      async16(Bbase + glOff[c] + k0, sB + rowS[c] * 8);
    }
    __syncthreads();
#pragma unroll
    for (int ks = 0; ks < 4; ++ks) {   // k = ks*16
      bf16x8 af[2], bfv[2];
#pragma unroll
      for (int i = 0; i < 2; ++i) {
        af[i]  = *(const bf16x8*)&sA[rowA[i] + colOff[ks]];
        bfv[i] = *(const bf16x8*)&sB[rowB[i] + colOff[ks]];
      }
#pragma unroll
      for (int i = 0; i < 2; ++i)
#pragma unroll
        for (int j = 0; j < 2; ++j)
          acc[i][j] = __builtin_amdgcn_mfma_f32_32x32x16_bf16(
              af[i], bfv[j], acc[i][j], 0, 0, 0);
    }
    __syncthreads();
  }
}

// -------- GEMM1: Q = x Wq^T + bq ; K = x Wk^T + bk  (z selects) --------
__global__ __launch_bounds__(256) void gemm_qk(
    const u16* __restrict__ X,
    const u16* __restrict__ Wq, const u16* __restrict__ Wk,
    const float* __restrict__ bq, const float* __restrict__ bk,
    u16* __restrict__ Qo, u16* __restrict__ Ko) {
  const u16* Bmat = blockIdx.z ? Wk : Wq;
  const float* bias = blockIdx.z ? bk : bq;
  u16* Out = blockIdx.z ? Ko : Qo;

  __shared__ u16 sA[128 * 64];
  __shared__ u16 sB[128 * 64];

  const int tid = threadIdx.x;
  const int lane = tid & 63;
  const int wid = tid >> 6;
  const int rowBase = blockIdx.y * 128;
  const int colBase = blockIdx.x * 128;
  const int wm = (wid >> 1) * 64;
  const int wn = (wid & 1) * 64;

  f32x16 acc[2][2] = {};
  gemm_mainloop_128(X + (size_t)rowBase * DIMK, Bmat + (size_t)colBase * DIMK,
                    sA, sB, acc, tid, wm, wn, lane);

  // C/D layout (32x32): col = lane&31, row = (r&3) + 8*(r>>2) + 4*(lane>>5)
  const int r31 = lane & 31;
  const int q4 = (lane >> 5) * 4;
#pragma unroll
  for (int j = 0; j < 2; ++j) {
    const int col = colBase + wn + j * 32 + r31;
    const float bv = bias[col];
#pragma unroll
    for (int i = 0; i < 2; ++i) {
#pragma unroll
      for (int r = 0; r < 16; ++r) {
        const int row = rowBase + wm + i * 32 + (r & 3) + 8 * (r >> 2) + q4;
        Out[(size_t)row * DIMK + col] = f32_to_bf16(acc[i][j][r] + bv);
      }
    }
  }
}

// -------- GEMM2: scores = scale * Q K^T  (bf16 in, fp32 out) --------
__global__ __launch_bounds__(256) void gemm_scores(
    const u16* __restrict__ Qi, const u16* __restrict__ Ki,
    float* __restrict__ out, float scale) {
  __shared__ u16 sA[128 * 64];
  __shared__ u16 sB[128 * 64];

  const int tid = threadIdx.x;
  const int lane = tid & 63;
  const int wid = tid >> 6;
  const int rowBase = blockIdx.y * 128;
  const int colBase = blockIdx.x * 128;
  const int wm = (wid >> 1) * 64;
  const int wn = (wid & 1) * 64;

  f32x16 acc[2][2] = {};
  gemm_mainloop_128(Qi + (size_t)rowBase * DIMK, Ki + (size_t)colBase * DIMK,
                    sA, sB, acc, tid, wm, wn, lane);

  const int r31 = lane & 31;
  const int q4 = (lane >> 5) * 4;
#pragma unroll
  for (int j = 0; j < 2; ++j) {
    const int col = colBase + wn + j * 32 + r31;
#pragma unroll
    for (int i = 0; i < 2; ++i) {
#pragma unroll
      for (int r = 0; r < 16; ++r) {
        const int row = rowBase + wm + i * 32 + (r & 3) + 8 * (r >> 2) + q4;
        out[(size_t)row * NSEQ + col] = acc[i][j][r] * scale;
      }
    }
  }
}

extern "C" void kernel_launch(void* const* d_in, const int* in_sizes, int n_in,
                              void* d_out, int out_size, void* d_ws, size_t ws_size,
                              hipStream_t stream) {
  const float* x = (const float*)d_in[0];
  const float* Wq = (const float*)d_in[1];
  const float* bq = (const float*)d_in[2];
  const float* Wk = (const float*)d_in[3];
  const float* bk = (const float*)d_in[4];
  // d_in[5], d_in[6] (W_v, b_v) unused — V never reaches the output.
  float* out = (float*)d_out;

  // workspace layout (64 MB total)
  u16* xb = (u16*)d_ws;                       // 4096x2048 bf16 (16 MB)
  u16* wqb = xb + (size_t)NSEQ * DIMK;        // 2048x2048 bf16 (8 MB)
  u16* wkb = wqb + (size_t)DIMK * DIMK;       // 8 MB
  u16* qb = wkb + (size_t)DIMK * DIMK;        // 16 MB
  u16* kb = qb + (size_t)NSEQ * DIMK;         // 16 MB

  const int totalN4 = (NSEQ * DIMK + 2 * DIMK * DIMK) / 4;
  cast3_f32_bf16<<<totalN4 / 256, 256, 0, stream>>>(x, Wq, Wk, xb, wqb, wkb);

  gemm_qk<<<dim3(DIMK / 128, NSEQ / 128, 2), 256, 0, stream>>>(xb, wqb, wkb, bq, bk,
                                                               qb, kb);

  const float scale = 1.0f / sqrtf((float)DIMK);
  gemm_scores<<<dim3(NSEQ / 128, NSEQ / 128, 1), 256, 0, stream>>>(qb, kb, out, scale);
}